// Round 8
// baseline (765.668 us; speedup 1.0000x reference)
//
#include <hip/hip_runtime.h>

typedef _Float16 f16;
typedef __attribute__((ext_vector_type(8))) _Float16 f16x8;
typedef __attribute__((ext_vector_type(4))) float f32x4;

#define CCH 2048   // channels after space_to_channel (32*4^3)
#define NSP 4096   // spatial after s2c (16^3)
#define NB  4      // batch

#define VMCNT8 asm volatile("s_waitcnt vmcnt(8)" ::: "memory")
#define VMCNT4 asm volatile("s_waitcnt vmcnt(4)" ::: "memory")
#define VMCNT0 asm volatile("s_waitcnt vmcnt(0)" ::: "memory")
#define CFENCE asm volatile("" ::: "memory")

__device__ __forceinline__ void gld16(const void* g, void* l) {
  __builtin_amdgcn_global_load_lds(
      (const __attribute__((address_space(1))) void*)g,
      (__attribute__((address_space(3))) void*)l, 16, 0, 0);
}

// ---------------- pack: x (B,32,64,64,64) fp32 -> qh/qv f16 [ib][cc][n] ----------------
// qh = fl16(q);  qv = fl16(2q - qh) = qh + 2*ql + d   (v-scheme for 2-product energy)
__global__ void pack_kernel(const float* __restrict__ x, f16* __restrict__ qh,
                            f16* __restrict__ qv, int b0) {
  int gid = blockIdx.x * 256 + threadIdx.x;
  int n = gid & (NSP - 1);
  int t = gid >> 12;
  int c = t & 31; t >>= 5;
  int r = t & 15; int ib = t >> 4;
  int wc = n >> 8, hc = (n >> 4) & 15, dc = n & 15;
  int w = wc * 4 + (hc >> 2);
  int h = (hc & 3) * 16 + r;
  int b = b0 + ib;
  const f32x4 v = *(const f32x4*)(x + ((((size_t)b * 32 + c) * 64 + w) * 64 + h) * 64 + dc * 4);
#pragma unroll
  for (int bd = 0; bd < 4; ++bd) {
    int cc = r * 128 + bd * 32 + c;
    size_t o = ((size_t)ib * CCH + cc) * NSP + n;
    float val = v[bd];
    f16 hi = (f16)val;
    qh[o] = hi;
    qv[o] = (f16)(2.0f * val - (float)hi);
  }
}

// ---------------- transpose: qh [ib][j][n] -> qhT [ib][n][j] ----------------
__global__ void transpose_kernel(const f16* __restrict__ qh, f16* __restrict__ qhT) {
  int ib = blockIdx.z;
  int j0 = blockIdx.x * 64, n0 = blockIdx.y * 64;
  __shared__ f16 tile[64][72];
  int t = threadIdx.x;
  int r = t >> 3;            // 0..31
  int cb = (t & 7) * 8;      // 0..56
#pragma unroll
  for (int half = 0; half < 2; ++half) {
    int rr = r + half * 32;
    f16x8 v = *(const f16x8*)(qh + ((size_t)ib * CCH + j0 + rr) * NSP + n0 + cb);
    *(f16x8*)&tile[rr][cb] = v;
  }
  __syncthreads();
#pragma unroll
  for (int half = 0; half < 2; ++half) {
    int rr = r + half * 32;
    f16x8 o;
#pragma unroll
    for (int u = 0; u < 8; ++u) o[u] = tile[cb + u][rr];
    *(f16x8*)(qhT + ((size_t)ib * NSP + n0 + rr) * CCH + j0 + cb) = o;
  }
}

// -------- GEMM1: energy = (qh v^T + v qh^T)/2, upper-triangle blocks, mirrored.
// 2 MFMA products per K-step (v-scheme), double-buffered 2-phase pipeline.
__global__ __launch_bounds__(256) void gemm1_kernel(const f16* __restrict__ qh,
                                                    const f16* __restrict__ qv,
                                                    float* __restrict__ energy) {
  int ib = blockIdx.z;
  // XCD-aware bijective swizzle: 136 = 8*17.
  int bx = blockIdx.x;
  int tri = (bx & 7) * 17 + (bx >> 3);
  // decode upper-triangle pair (bi <= bj) from linear id (136 pairs)
  int rem = tri, bi = 0, span = 16;
  while (rem >= span) { rem -= span; ++bi; --span; }
  int bj = bi + rem;
  int i0 = bi * 128, j0 = bj * 128;
  float* eout = energy + (size_t)ib * CCH * CCH;

  __shared__ f16 Lds[2][4][128 * 32];   // [buf][Ah,Av,Bh,Bv] = 64 KB
  int tid = threadIdx.x;
  int lane = tid & 63, wv = tid >> 6;
  int l15 = lane & 15, quad = lane >> 4;
  int wr = (wv >> 1) * 64, wcol = (wv & 1) * 64;
  int swz = (l15 >> 1) & 3;                       // fragment-read bank swizzle
  int kbs = (lane & 3) ^ ((lane >> 3) & 3);       // staging-side swizzle (per-lane)

  const f16* srcA = (wv & 1) ? qv : qh;
  int rbase = (wv < 2) ? i0 : j0;
  const f16* gsrc = srcA + ((size_t)ib * CCH + rbase) * NSP
                    + (size_t)(lane >> 2) * NSP + kbs * 8;

  auto stage = [&](int buf, int kk) {
    f16* ld = &Lds[buf][wv][0];
#pragma unroll
    for (int t = 0; t < 8; ++t)
      gld16(gsrc + (size_t)(t * 16) * NSP + kk, ld + t * 512);
  };

  const f32x4 vzero = {0.f, 0.f, 0.f, 0.f};
  f32x4 acc[4][4];
#pragma unroll
  for (int a = 0; a < 4; ++a)
#pragma unroll
    for (int bq = 0; bq < 4; ++bq) acc[a][bq] = vzero;

  const int nk = NSP >> 5;   // 128
  stage(0, 0);
  __syncthreads();                                  // drain prologue stage
  for (int it = 0; it < nk; ++it) {
    int cur = it & 1;
    if (it + 1 < nk) stage(cur ^ 1, (it + 1) << 5);  // prefetch next
    f16x8 ah[4], av[4], bh[4], bv[4];
#pragma unroll
    for (int mt = 0; mt < 4; ++mt) {
      int row = wr + mt * 16 + l15;
      ah[mt] = *(const f16x8*)&Lds[cur][0][row * 32 + ((quad ^ swz) * 8)];
      av[mt] = *(const f16x8*)&Lds[cur][1][row * 32 + ((quad ^ swz) * 8)];
    }
#pragma unroll
    for (int nt = 0; nt < 4; ++nt) {
      int col = wcol + nt * 16 + l15;
      bh[nt] = *(const f16x8*)&Lds[cur][2][col * 32 + ((quad ^ swz) * 8)];
      bv[nt] = *(const f16x8*)&Lds[cur][3][col * 32 + ((quad ^ swz) * 8)];
    }
    __builtin_amdgcn_s_setprio(1);
#pragma unroll
    for (int mt = 0; mt < 4; ++mt)
#pragma unroll
      for (int nt = 0; nt < 4; ++nt) {
        // P1 = qh_i . v_j  ;  P2 = v_i . qh_j  ;  E_tile = (P1+P2)/2
        acc[mt][nt] = __builtin_amdgcn_mfma_f32_16x16x32_f16(ah[mt], bv[nt], acc[mt][nt], 0, 0, 0);
        acc[mt][nt] = __builtin_amdgcn_mfma_f32_16x16x32_f16(av[mt], bh[nt], acc[mt][nt], 0, 0, 0);
      }
    __builtin_amdgcn_s_setprio(0);
    __syncthreads();   // drains this iter's prefetch + releases cur for overwrite
  }
  bool diag = (bi == bj);
#pragma unroll
  for (int mt = 0; mt < 4; ++mt)
#pragma unroll
    for (int nt = 0; nt < 4; ++nt)
#pragma unroll
      for (int rg = 0; rg < 4; ++rg) {
        int row = i0 + wr + mt * 16 + quad * 4 + rg;
        int col = j0 + wcol + nt * 16 + l15;
        float v = 0.5f * acc[mt][nt][rg];
        eout[(size_t)row * CCH + col] = v;
        if (!diag) eout[(size_t)col * CCH + row] = v;
      }
}

// ------- softmax: attn[i][j] = gamma * exp(rowmin - E)/sum + (i==j), f16 out ----
__global__ void softmax_kernel(const float* __restrict__ e0,
                               const float* __restrict__ gamma_p,
                               f16* __restrict__ attn) {
  int i = blockIdx.x, ib = blockIdx.y;
  const float* r0 = e0 + ((size_t)ib * CCH + i) * CCH;
  f16* arow = attn + ((size_t)ib * CCH + i) * CCH;
  int t = threadIdx.x;
  f32x4 v0 = *(const f32x4*)(r0 + t * 8);
  f32x4 v1 = *(const f32x4*)(r0 + t * 8 + 4);
  float m = v0[0];
#pragma unroll
  for (int u = 1; u < 4; ++u) m = fminf(m, v0[u]);
#pragma unroll
  for (int u = 0; u < 4; ++u) m = fminf(m, v1[u]);
#pragma unroll
  for (int off = 32; off > 0; off >>= 1) m = fminf(m, __shfl_xor(m, off));
  __shared__ float redA[4], redB[4];
  if ((t & 63) == 0) redA[t >> 6] = m;
  __syncthreads();
  m = fminf(fminf(redA[0], redA[1]), fminf(redA[2], redA[3]));
  float e[8], s = 0.f;
#pragma unroll
  for (int u = 0; u < 4; ++u) { e[u] = __expf(m - v0[u]); s += e[u]; }
#pragma unroll
  for (int u = 0; u < 4; ++u) { e[4 + u] = __expf(m - v1[u]); s += e[4 + u]; }
#pragma unroll
  for (int off = 32; off > 0; off >>= 1) s += __shfl_xor(s, off);
  if ((t & 63) == 0) redB[t >> 6] = s;
  __syncthreads();
  s = redB[0] + redB[1] + redB[2] + redB[3];
  float gamma = *gamma_p;
  float ginv = gamma / s;
  int du = i - t * 8;   // in [0,8) only for the thread owning the diagonal element
  f16x8 o;
#pragma unroll
  for (int u = 0; u < 8; ++u) {
    float v = e[u] * ginv;
    if (u == du) v += 1.0f;
    o[u] = (f16)v;
  }
  *(f16x8*)(arow + t * 8) = o;
}

// ---------------- GEMM2: out = c2s(attn' @ q), attn' = gamma*attn + I ----
// 4-slot LDS queue, counted-vmcnt deep pipeline, XCD-swizzled,
// LDS-staged fully-coalesced f32x4 epilogue.
__global__ __launch_bounds__(256) void gemm2_kernel(const f16* __restrict__ attn,
                                                    const f16* __restrict__ qhT,
                                                    float* __restrict__ out, int b0) {
  int ib = blockIdx.z;
  // XCD-aware bijective swizzle over the 16x32 = 512 (x,y) block space.
  int lin = blockIdx.x + gridDim.x * blockIdx.y;           // 0..511
  int nwg = gridDim.x * gridDim.y;
  int cpx = nwg >> 3;
  int lin2 = (lin & 7) * cpx + (lin >> 3);
  int i0 = (lin2 & 15) * 128;      // channel (cd) tile
  int n0 = (lin2 >> 4) * 128;      // spatial (n) tile
  // 4 slots x {A,B} x 8KB = 64 KB; reused as 16384 f32 for the epilogue.
  __shared__ f16 Lds[4][2][128 * 32];
  int tid = threadIdx.x;
  int lane = tid & 63, wv = tid >> 6;
  int l15 = lane & 15, quad = lane >> 4;
  int wr = (wv >> 1) * 64, wcol = (wv & 1) * 64;
  int swz = (l15 >> 1) & 3;
  int kbs = (lane & 3) ^ ((lane >> 3) & 3);

  int arr = wv >> 1, rh = wv & 1;     // arr 0 -> A (attn rows i0..), 1 -> B (qhT rows n0..)
  const f16* gbase = arr ? (qhT + ((size_t)ib * NSP + n0) * CCH)
                         : (attn + ((size_t)ib * CCH + i0) * CCH);
  const f16* gsrc = gbase + (size_t)(rh * 64 + (lane >> 2)) * CCH + kbs * 8;

  auto stage = [&](int slot, int kk) {
#pragma unroll
    for (int t = 0; t < 4; ++t)
      gld16(gsrc + (size_t)(t * 16) * CCH + kk,
            &Lds[slot][arr][(rh * 64 + t * 16) * 32]);
  };

  const f32x4 vzero = {0.f, 0.f, 0.f, 0.f};
  f32x4 acc[4][4];
#pragma unroll
  for (int a = 0; a < 4; ++a)
#pragma unroll
    for (int bq = 0; bq < 4; ++bq) acc[a][bq] = vzero;

  const int NP = CCH / 32;   // 64 phases
  stage(0, 0); stage(1, 32); stage(2, 64);
  for (int p = 0; p < NP; ++p) {
    int remp = NP - 1 - p;
    if (remp >= 2) { VMCNT8; } else if (remp == 1) { VMCNT4; } else { VMCNT0; }
    __builtin_amdgcn_s_barrier();
    CFENCE;
    if (p + 3 < NP) stage((p + 3) & 3, (p + 3) << 5);
    int s = p & 3;
    const f16* As = &Lds[s][0][0];
    const f16* Bs = &Lds[s][1][0];
    f16x8 af[4], bf[4];
#pragma unroll
    for (int mt = 0; mt < 4; ++mt)
      af[mt] = *(const f16x8*)&As[(wr + mt * 16 + l15) * 32 + ((quad ^ swz) * 8)];
#pragma unroll
    for (int nt = 0; nt < 4; ++nt)
      bf[nt] = *(const f16x8*)&Bs[(wcol + nt * 16 + l15) * 32 + ((quad ^ swz) * 8)];
    __builtin_amdgcn_s_setprio(1);
#pragma unroll
    for (int mt = 0; mt < 4; ++mt)
#pragma unroll
      for (int nt = 0; nt < 4; ++nt)
        acc[mt][nt] = __builtin_amdgcn_mfma_f32_16x16x32_f16(af[mt], bf[nt], acc[mt][nt], 0, 0, 0);
    __builtin_amdgcn_s_setprio(0);
  }

  __syncthreads();   // all waves done with LDS slots before epilogue reuse
  // ---- epilogue: acc -> LDS [g][ihh][id][f] f32, then fully-coalesced store ----
  float* eld = (float*)&Lds[0][0][0];   // 16384 f32 = 64 KB
#pragma unroll
  for (int mt = 0; mt < 4; ++mt) {
    int f = (wr >> 5) + (mt >> 1);          // (i>>5)&3
    int gb = (mt & 1) * 16 + quad * 4;      // i&31 base
#pragma unroll
    for (int nt = 0; nt < 4; ++nt) {
      int jh = (wcol >> 4) + nt;            // ihh - ihh0, 0..7
#pragma unroll
      for (int rg = 0; rg < 4; ++rg)
        eld[(gb + rg) * 512 + jh * 64 + l15 * 4 + f] = acc[mt][nt][rg];
    }
  }
  __syncthreads();
  int b = b0 + ib;
  int e = i0 >> 7;                          // fixed per block
  int iw = n0 >> 8;
  int W = iw * 4 + (e >> 2);
  int H0 = (e & 3) * 16 + ((n0 >> 4) & 15); // ihh0 in {0,8}
#pragma unroll
  for (int u = 0; u < 8; ++u) {
    int g = wv * 8 + u;
    size_t goff = ((((size_t)b * 32 + g) * 64 + W) * 4096) + (size_t)H0 * 64;
#pragma unroll
    for (int hv = 0; hv < 2; ++hv) {
      int fo = hv * 256 + lane * 4;
      *(f32x4*)(out + goff + fo) = *(const f32x4*)&eld[g * 512 + fo];
    }
  }
}

extern "C" void kernel_launch(void* const* d_in, const int* in_sizes, int n_in,
                              void* d_out, int out_size, void* d_ws, size_t ws_size,
                              hipStream_t stream) {
  const float* x = (const float*)d_in[0];
  const float* gamma = (const float*)d_in[1];
  float* out = (float*)d_out;

  const size_t szQ = (size_t)CCH * NSP;  // 8M elements
  const size_t szE = (size_t)CCH * CCH;  // 4M elements

  // bytes per batch: qh + qv + qhT f16 + energy fp32 + attn f16 = 72 MB
  const size_t pb = szQ * 2 * 3 + szE * 4 + szE * 2;

  int nb = (ws_size >= (size_t)NB * pb) ? NB : 1;

  char* p = (char*)d_ws;
  f16* qh = (f16*)p;   p += (size_t)nb * szQ * 2;
  f16* qv = (f16*)p;   p += (size_t)nb * szQ * 2;
  f16* qhT = (f16*)p;  p += (size_t)nb * szQ * 2;
  float* energy = (float*)p; p += (size_t)nb * szE * 4;
  f16* attn = (f16*)p;

  for (int b0 = 0; b0 < NB; b0 += nb) {
    pack_kernel<<<nb * 8192, 256, 0, stream>>>(x, qh, qv, b0);
    transpose_kernel<<<dim3(32, 64, nb), 256, 0, stream>>>(qh, qhT);
    gemm1_kernel<<<dim3(136, 1, nb), 256, 0, stream>>>(qh, qv, energy);
    softmax_kernel<<<dim3(CCH, nb), 256, 0, stream>>>(energy, gamma, attn);
    gemm2_kernel<<<dim3(16, 32, nb), 256, 0, stream>>>(attn, qhT, out, b0);
  }
}

// Round 9
// 749.005 us; speedup vs baseline: 1.0222x; 1.0222x over previous
//
#include <hip/hip_runtime.h>

typedef _Float16 f16;
typedef __attribute__((ext_vector_type(8))) _Float16 f16x8;
typedef __attribute__((ext_vector_type(4))) float f32x4;

#define CCH 2048   // channels after space_to_channel (32*4^3)
#define NSP 4096   // spatial after s2c (16^3)
#define NB  4      // batch

__device__ __forceinline__ void gld16(const void* g, void* l) {
  __builtin_amdgcn_global_load_lds(
      (const __attribute__((address_space(1))) void*)g,
      (__attribute__((address_space(3))) void*)l, 16, 0, 0);
}

// ---------------- pack: x (B,32,64,64,64) fp32 -> qh/ql f16 [ib][cc][n] ----------------
__global__ void pack_kernel(const float* __restrict__ x, f16* __restrict__ qh,
                            f16* __restrict__ ql, int b0) {
  int gid = blockIdx.x * 256 + threadIdx.x;
  int n = gid & (NSP - 1);
  int t = gid >> 12;
  int c = t & 31; t >>= 5;
  int r = t & 15; int ib = t >> 4;
  int wc = n >> 8, hc = (n >> 4) & 15, dc = n & 15;
  int w = wc * 4 + (hc >> 2);
  int h = (hc & 3) * 16 + r;
  int b = b0 + ib;
  const f32x4 v = *(const f32x4*)(x + ((((size_t)b * 32 + c) * 64 + w) * 64 + h) * 64 + dc * 4);
#pragma unroll
  for (int bd = 0; bd < 4; ++bd) {
    int cc = r * 128 + bd * 32 + c;
    size_t o = ((size_t)ib * CCH + cc) * NSP + n;
    float val = v[bd];
    f16 hi = (f16)val;
    qh[o] = hi;
    ql[o] = (f16)(val - (float)hi);
  }
}

// ---------------- transpose: qh [ib][j][n] -> qhT [ib][n][j] ----------------
__global__ void transpose_kernel(const f16* __restrict__ qh, f16* __restrict__ qhT) {
  int ib = blockIdx.z;
  int j0 = blockIdx.x * 64, n0 = blockIdx.y * 64;
  __shared__ f16 tile[64][72];
  int t = threadIdx.x;
  int r = t >> 3;            // 0..31
  int cb = (t & 7) * 8;      // 0..56
#pragma unroll
  for (int half = 0; half < 2; ++half) {
    int rr = r + half * 32;
    f16x8 v = *(const f16x8*)(qh + ((size_t)ib * CCH + j0 + rr) * NSP + n0 + cb);
    *(f16x8*)&tile[rr][cb] = v;
  }
  __syncthreads();
#pragma unroll
  for (int half = 0; half < 2; ++half) {
    int rr = r + half * 32;
    f16x8 o;
#pragma unroll
    for (int u = 0; u < 8; ++u) o[u] = tile[cb + u][rr];
    *(f16x8*)(qhT + ((size_t)ib * NSP + n0 + rr) * CCH + j0 + cb) = o;
  }
}

// -------- GEMM1: energy = q q^T, split f16 (hh+hl+lh), upper-triangle blocks,
// -------- double-buffered 2-phase pipeline (round-3/7 proven structure, ksplit=1).
__global__ __launch_bounds__(256) void gemm1_kernel(const f16* __restrict__ qh,
                                                    const f16* __restrict__ ql,
                                                    float* __restrict__ energy) {
  int ib = blockIdx.z;
  // XCD-aware bijective swizzle: 136 = 8*17.
  int bx = blockIdx.x;
  int tri = (bx & 7) * 17 + (bx >> 3);
  // decode upper-triangle pair (bi <= bj) from linear id (136 pairs)
  int rem = tri, bi = 0, span = 16;
  while (rem >= span) { rem -= span; ++bi; --span; }
  int bj = bi + rem;
  int i0 = bi * 128, j0 = bj * 128;
  float* eout = energy + (size_t)ib * CCH * CCH;

  __shared__ f16 Lds[2][4][128 * 32];   // [buf][Ah,Al,Bh,Bl] = 64 KB
  int tid = threadIdx.x;
  int lane = tid & 63, wv = tid >> 6;
  int l15 = lane & 15, quad = lane >> 4;
  int wr = (wv >> 1) * 64, wcol = (wv & 1) * 64;
  int swz = (l15 >> 1) & 3;                       // fragment-read bank swizzle
  int kbs = (lane & 3) ^ ((lane >> 3) & 3);       // staging-side swizzle (per-lane)

  const f16* srcA = (wv & 1) ? ql : qh;
  int rbase = (wv < 2) ? i0 : j0;
  const f16* gsrc = srcA + ((size_t)ib * CCH + rbase) * NSP
                    + (size_t)(lane >> 2) * NSP + kbs * 8;

  auto stage = [&](int buf, int kk) {
    f16* ld = &Lds[buf][wv][0];
#pragma unroll
    for (int t = 0; t < 8; ++t)
      gld16(gsrc + (size_t)(t * 16) * NSP + kk, ld + t * 512);
  };

  const f32x4 vzero = {0.f, 0.f, 0.f, 0.f};
  f32x4 acc[4][4];
#pragma unroll
  for (int a = 0; a < 4; ++a)
#pragma unroll
    for (int bq = 0; bq < 4; ++bq) acc[a][bq] = vzero;

  const int nk = NSP >> 5;   // 128
  stage(0, 0);
  __syncthreads();                                  // drain prologue stage
  for (int it = 0; it < nk; ++it) {
    int cur = it & 1;
    if (it + 1 < nk) stage(cur ^ 1, (it + 1) << 5);  // prefetch next
    f16x8 ah[4], al[4], bh[4], bl[4];
#pragma unroll
    for (int mt = 0; mt < 4; ++mt) {
      int row = wr + mt * 16 + l15;
      ah[mt] = *(const f16x8*)&Lds[cur][0][row * 32 + ((quad ^ swz) * 8)];
      al[mt] = *(const f16x8*)&Lds[cur][1][row * 32 + ((quad ^ swz) * 8)];
    }
#pragma unroll
    for (int nt = 0; nt < 4; ++nt) {
      int col = wcol + nt * 16 + l15;
      bh[nt] = *(const f16x8*)&Lds[cur][2][col * 32 + ((quad ^ swz) * 8)];
      bl[nt] = *(const f16x8*)&Lds[cur][3][col * 32 + ((quad ^ swz) * 8)];
    }
    __builtin_amdgcn_s_setprio(1);
#pragma unroll
    for (int mt = 0; mt < 4; ++mt)
#pragma unroll
      for (int nt = 0; nt < 4; ++nt) {
        acc[mt][nt] = __builtin_amdgcn_mfma_f32_16x16x32_f16(ah[mt], bh[nt], acc[mt][nt], 0, 0, 0);
        acc[mt][nt] = __builtin_amdgcn_mfma_f32_16x16x32_f16(ah[mt], bl[nt], acc[mt][nt], 0, 0, 0);
        acc[mt][nt] = __builtin_amdgcn_mfma_f32_16x16x32_f16(al[mt], bh[nt], acc[mt][nt], 0, 0, 0);
      }
    __builtin_amdgcn_s_setprio(0);
    __syncthreads();   // drains this iter's prefetch + releases cur for overwrite
  }
  bool diag = (bi == bj);
#pragma unroll
  for (int mt = 0; mt < 4; ++mt)
#pragma unroll
    for (int nt = 0; nt < 4; ++nt)
#pragma unroll
      for (int rg = 0; rg < 4; ++rg) {
        int row = i0 + wr + mt * 16 + quad * 4 + rg;
        int col = j0 + wcol + nt * 16 + l15;
        float v = acc[mt][nt][rg];
        eout[(size_t)row * CCH + col] = v;
        if (!diag) eout[(size_t)col * CCH + row] = v;
      }
}

// ------- softmax: attn[i][j] = gamma * exp(rowmin - E)/sum + (i==j), f16 out ----
__global__ void softmax_kernel(const float* __restrict__ e0,
                               const float* __restrict__ gamma_p,
                               f16* __restrict__ attn) {
  int i = blockIdx.x, ib = blockIdx.y;
  const float* r0 = e0 + ((size_t)ib * CCH + i) * CCH;
  f16* arow = attn + ((size_t)ib * CCH + i) * CCH;
  int t = threadIdx.x;
  f32x4 v0 = *(const f32x4*)(r0 + t * 8);
  f32x4 v1 = *(const f32x4*)(r0 + t * 8 + 4);
  float m = v0[0];
#pragma unroll
  for (int u = 1; u < 4; ++u) m = fminf(m, v0[u]);
#pragma unroll
  for (int u = 0; u < 4; ++u) m = fminf(m, v1[u]);
#pragma unroll
  for (int off = 32; off > 0; off >>= 1) m = fminf(m, __shfl_xor(m, off));
  __shared__ float redA[4], redB[4];
  if ((t & 63) == 0) redA[t >> 6] = m;
  __syncthreads();
  m = fminf(fminf(redA[0], redA[1]), fminf(redA[2], redA[3]));
  float e[8], s = 0.f;
#pragma unroll
  for (int u = 0; u < 4; ++u) { e[u] = __expf(m - v0[u]); s += e[u]; }
#pragma unroll
  for (int u = 0; u < 4; ++u) { e[4 + u] = __expf(m - v1[u]); s += e[4 + u]; }
#pragma unroll
  for (int off = 32; off > 0; off >>= 1) s += __shfl_xor(s, off);
  if ((t & 63) == 0) redB[t >> 6] = s;
  __syncthreads();
  s = redB[0] + redB[1] + redB[2] + redB[3];
  float gamma = *gamma_p;
  float ginv = gamma / s;
  int du = i - t * 8;   // in [0,8) only for the thread owning the diagonal element
  f16x8 o;
#pragma unroll
  for (int u = 0; u < 8; ++u) {
    float v = e[u] * ginv;
    if (u == du) v += 1.0f;
    o[u] = (f16)v;
  }
  *(f16x8*)(arow + t * 8) = o;
}

// ---------------- GEMM2: out = c2s(attn' @ q), attn' = gamma*attn + I ----
// 256x256 tile (128 FLOP/byte feed intensity), 512 threads / 8 waves,
// double-buffered 2-barrier pipeline, XCD-swizzled, 4-phase staged epilogue.
__global__ __launch_bounds__(512) void gemm2_kernel(const f16* __restrict__ attn,
                                                    const f16* __restrict__ qhT,
                                                    float* __restrict__ out, int b0) {
  int ib = blockIdx.z;
  // XCD-aware bijective swizzle over the 8x16 = 128 (x,y) block space.
  int lin = blockIdx.x + gridDim.x * blockIdx.y;           // 0..127
  int nwg = gridDim.x * gridDim.y;
  int cpx = nwg >> 3;                                      // 16
  int lin2 = (lin & 7) * cpx + (lin >> 3);
  int i0 = (lin2 & 7) * 256;       // channel (cd) tile
  int n0 = (lin2 >> 3) * 256;      // spatial (n) tile
  // 2 bufs x {A,B} x 256x32 f16 = 64 KB; reused as 16384 f32 for the epilogue.
  __shared__ f16 Lds[2][2][256 * 32];
  int tid = threadIdx.x;
  int lane = tid & 63, wv = tid >> 6;        // wv 0..7
  int l15 = lane & 15, quad = lane >> 4;
  int wr = (wv >> 2) * 128;                  // ch offset: 0 or 128
  int wcol = (wv & 3) * 64;                  // n offset: 0,64,128,192
  int swz = (l15 >> 1) & 3;
  int kbs = (lane & 3) ^ ((lane >> 3) & 3);

  int arr = wv >> 2, rsub = wv & 3;   // staging role: arr 0 -> A (attn), 1 -> B (qhT)
  const f16* gbase = arr ? (qhT + ((size_t)ib * NSP + n0) * CCH)
                         : (attn + ((size_t)ib * CCH + i0) * CCH);
  const f16* gsrc = gbase + (size_t)(rsub * 64 + (lane >> 2)) * CCH + kbs * 8;

  auto stage = [&](int buf, int kk) {
#pragma unroll
    for (int t = 0; t < 4; ++t)
      gld16(gsrc + (size_t)(t * 16) * CCH + kk,
            &Lds[buf][arr][(rsub * 64 + t * 16) * 32]);
  };

  const f32x4 vzero = {0.f, 0.f, 0.f, 0.f};
  f32x4 acc[8][4];
#pragma unroll
  for (int a = 0; a < 8; ++a)
#pragma unroll
    for (int bq = 0; bq < 4; ++bq) acc[a][bq] = vzero;

  const int nk = CCH >> 5;   // 64
  stage(0, 0);
  __syncthreads();
  for (int it = 0; it < nk; ++it) {
    int cur = it & 1;
    if (it + 1 < nk) stage(cur ^ 1, (it + 1) << 5);
    f16x8 af[8], bf[4];
#pragma unroll
    for (int mt = 0; mt < 8; ++mt)
      af[mt] = *(const f16x8*)&Lds[cur][0][(wr + mt * 16 + l15) * 32 + ((quad ^ swz) * 8)];
#pragma unroll
    for (int nt = 0; nt < 4; ++nt)
      bf[nt] = *(const f16x8*)&Lds[cur][1][(wcol + nt * 16 + l15) * 32 + ((quad ^ swz) * 8)];
    __builtin_amdgcn_s_setprio(1);
#pragma unroll
    for (int mt = 0; mt < 8; ++mt)
#pragma unroll
      for (int nt = 0; nt < 4; ++nt)
        acc[mt][nt] = __builtin_amdgcn_mfma_f32_16x16x32_f16(af[mt], bf[nt], acc[mt][nt], 0, 0, 0);
    __builtin_amdgcn_s_setprio(0);
    __syncthreads();
  }

  // ---- epilogue: 4 phases of (ch-half h, n-half nh); each phase stages a
  // ---- 128ch x 128n unit as [g][jh][id][f] f32 in LDS, then coalesced store.
  float* eld = (float*)&Lds[0][0][0];   // 16384 f32 = 64 KB
  int b = b0 + ib;
#pragma unroll
  for (int p = 0; p < 4; ++p) {
    __syncthreads();
    if ((wv >> 1) == p) {               // 2 waves own this 128x128 unit
#pragma unroll
      for (int mt = 0; mt < 8; ++mt) {
        int f = mt >> 1;                 // (ch>>5)&3
        int gb2 = (mt & 1) * 16 + quad * 4;  // ch&31 base
#pragma unroll
        for (int nt = 0; nt < 4; ++nt) {
          int jh = (wv & 1) * 4 + nt;    // ihh-local 0..7
#pragma unroll
          for (int rg = 0; rg < 4; ++rg)
            eld[(gb2 + rg) * 512 + jh * 64 + l15 * 4 + f] = acc[mt][nt][rg];
        }
      }
    }
    __syncthreads();
    int h = p >> 1, nh = p & 1;
    int e = (i0 >> 7) + h;
    int W = (n0 >> 8) * 4 + (e >> 2);
    int H0 = (e & 3) * 16 + nh * 8;
#pragma unroll
    for (int u = 0; u < 4; ++u) {
      int g = wv * 4 + u;
      size_t goff = ((((size_t)b * 32 + g) * 64 + W) * 4096) + (size_t)H0 * 64;
#pragma unroll
      for (int hv = 0; hv < 2; ++hv) {
        int fo = hv * 256 + lane * 4;
        *(f32x4*)(out + goff + fo) = *(const f32x4*)&eld[g * 512 + fo];
      }
    }
  }
}

extern "C" void kernel_launch(void* const* d_in, const int* in_sizes, int n_in,
                              void* d_out, int out_size, void* d_ws, size_t ws_size,
                              hipStream_t stream) {
  const float* x = (const float*)d_in[0];
  const float* gamma = (const float*)d_in[1];
  float* out = (float*)d_out;

  const size_t szQ = (size_t)CCH * NSP;  // 8M elements
  const size_t szE = (size_t)CCH * CCH;  // 4M elements

  // bytes per batch: qh + ql + qhT f16 + energy fp32 + attn f16 = 72 MB
  const size_t pb = szQ * 2 * 3 + szE * 4 + szE * 2;

  int nb = (ws_size >= (size_t)NB * pb) ? NB : 1;

  char* p = (char*)d_ws;
  f16* qh = (f16*)p;   p += (size_t)nb * szQ * 2;
  f16* ql = (f16*)p;   p += (size_t)nb * szQ * 2;
  f16* qhT = (f16*)p;  p += (size_t)nb * szQ * 2;
  float* energy = (float*)p; p += (size_t)nb * szE * 4;
  f16* attn = (f16*)p;

  for (int b0 = 0; b0 < NB; b0 += nb) {
    pack_kernel<<<nb * 8192, 256, 0, stream>>>(x, qh, ql, b0);
    transpose_kernel<<<dim3(32, 64, nb), 256, 0, stream>>>(qh, qhT);
    gemm1_kernel<<<dim3(136, 1, nb), 256, 0, stream>>>(qh, ql, energy);
    softmax_kernel<<<dim3(CCH, nb), 256, 0, stream>>>(energy, gamma, attn);
    gemm2_kernel<<<dim3(8, 16, nb), 512, 0, stream>>>(attn, qhT, out, b0);
  }
}

// Round 10
// 689.248 us; speedup vs baseline: 1.1109x; 1.0867x over previous
//
#include <hip/hip_runtime.h>

typedef _Float16 f16;
typedef __attribute__((ext_vector_type(8))) _Float16 f16x8;
typedef __attribute__((ext_vector_type(4))) float f32x4;

#define CCH 2048   // channels after space_to_channel (32*4^3)
#define NSP 4096   // spatial after s2c (16^3)
#define NB  4      // batch

__device__ __forceinline__ void gld16(const void* g, void* l) {
  __builtin_amdgcn_global_load_lds(
      (const __attribute__((address_space(1))) void*)g,
      (__attribute__((address_space(3))) void*)l, 16, 0, 0);
}

// ---------------- pack: x (B,32,64,64,64) fp32 -> qh/ql f16 [ib][cc][n] ----------------
__global__ void pack_kernel(const float* __restrict__ x, f16* __restrict__ qh,
                            f16* __restrict__ ql, int b0) {
  int gid = blockIdx.x * 256 + threadIdx.x;
  int n = gid & (NSP - 1);
  int t = gid >> 12;
  int c = t & 31; t >>= 5;
  int r = t & 15; int ib = t >> 4;
  int wc = n >> 8, hc = (n >> 4) & 15, dc = n & 15;
  int w = wc * 4 + (hc >> 2);
  int h = (hc & 3) * 16 + r;
  int b = b0 + ib;
  const f32x4 v = *(const f32x4*)(x + ((((size_t)b * 32 + c) * 64 + w) * 64 + h) * 64 + dc * 4);
#pragma unroll
  for (int bd = 0; bd < 4; ++bd) {
    int cc = r * 128 + bd * 32 + c;
    size_t o = ((size_t)ib * CCH + cc) * NSP + n;
    float val = v[bd];
    f16 hi = (f16)val;
    qh[o] = hi;
    ql[o] = (f16)(val - (float)hi);
  }
}

// ---------------- transpose: qh [ib][j][n] -> qhT [ib][n][j] ----------------
__global__ void transpose_kernel(const f16* __restrict__ qh, f16* __restrict__ qhT) {
  int ib = blockIdx.z;
  int j0 = blockIdx.x * 64, n0 = blockIdx.y * 64;
  __shared__ f16 tile[64][72];
  int t = threadIdx.x;
  int r = t >> 3;            // 0..31
  int cb = (t & 7) * 8;      // 0..56
#pragma unroll
  for (int half = 0; half < 2; ++half) {
    int rr = r + half * 32;
    f16x8 v = *(const f16x8*)(qh + ((size_t)ib * CCH + j0 + rr) * NSP + n0 + cb);
    *(f16x8*)&tile[rr][cb] = v;
  }
  __syncthreads();
#pragma unroll
  for (int half = 0; half < 2; ++half) {
    int rr = r + half * 32;
    f16x8 o;
#pragma unroll
    for (int u = 0; u < 8; ++u) o[u] = tile[cb + u][rr];
    *(f16x8*)(qhT + ((size_t)ib * NSP + n0 + rr) * CCH + j0 + cb) = o;
  }
}

// -------- GEMM1: energy = q q^T, split f16 (hh+hl+lh), upper-triangle blocks,
// -------- double-buffered 2-phase pipeline, ksplit=2 K-partition:
// -------- 1088 blocks -> 3 full cohorts at 2 blocks/CU (cohort quantization fix),
// -------- half-K panels also halve the L2 working set (FETCH ~halves).
__global__ __launch_bounds__(256) void gemm1_kernel(const f16* __restrict__ qh,
                                                    const f16* __restrict__ ql,
                                                    float* __restrict__ energy,
                                                    int ksplit) {
  int ib = blockIdx.z;
  // XCD-aware bijective swizzle: grid.x is 136 or 272, both divisible by 8.
  int nwg = gridDim.x;
  int cpx = nwg >> 3;
  int bx = blockIdx.x;
  int tri = (bx & 7) * cpx + (bx >> 3);
  int ks = 0;
  if (ksplit == 2) { ks = tri >= 136; tri -= ks * 136; }
  // decode upper-triangle pair (bi <= bj) from linear id (136 pairs)
  int rem = tri, bi = 0, span = 16;
  while (rem >= span) { rem -= span; ++bi; --span; }
  int bj = bi + rem;
  int i0 = bi * 128, j0 = bj * 128;
  int kbeg = ks * 2048;
  int kend = (ksplit == 2) ? kbeg + 2048 : NSP;
  float* eout = energy + ((size_t)(ks * gridDim.z + ib)) * CCH * CCH;

  __shared__ f16 Lds[2][4][128 * 32];   // [buf][Ah,Al,Bh,Bl] = 64 KB
  int tid = threadIdx.x;
  int lane = tid & 63, wv = tid >> 6;
  int l15 = lane & 15, quad = lane >> 4;
  int wr = (wv >> 1) * 64, wcol = (wv & 1) * 64;
  int swz = (l15 >> 1) & 3;                       // fragment-read bank swizzle
  int kbs = (lane & 3) ^ ((lane >> 3) & 3);       // staging-side swizzle (per-lane)

  const f16* srcA = (wv & 1) ? ql : qh;
  int rbase = (wv < 2) ? i0 : j0;
  const f16* gsrc = srcA + ((size_t)ib * CCH + rbase) * NSP
                    + (size_t)(lane >> 2) * NSP + kbs * 8;

  auto stage = [&](int buf, int kk) {
    f16* ld = &Lds[buf][wv][0];
#pragma unroll
    for (int t = 0; t < 8; ++t)
      gld16(gsrc + (size_t)(t * 16) * NSP + kk, ld + t * 512);
  };

  const f32x4 vzero = {0.f, 0.f, 0.f, 0.f};
  f32x4 acc[4][4];
#pragma unroll
  for (int a = 0; a < 4; ++a)
#pragma unroll
    for (int bq = 0; bq < 4; ++bq) acc[a][bq] = vzero;

  int nk = (kend - kbeg) >> 5;
  stage(0, kbeg);
  __syncthreads();                                  // drain prologue stage
  for (int it = 0; it < nk; ++it) {
    int cur = it & 1;
    if (it + 1 < nk) stage(cur ^ 1, kbeg + ((it + 1) << 5));  // prefetch next
    f16x8 ah[4], al[4], bh[4], bl[4];
#pragma unroll
    for (int mt = 0; mt < 4; ++mt) {
      int row = wr + mt * 16 + l15;
      ah[mt] = *(const f16x8*)&Lds[cur][0][row * 32 + ((quad ^ swz) * 8)];
      al[mt] = *(const f16x8*)&Lds[cur][1][row * 32 + ((quad ^ swz) * 8)];
    }
#pragma unroll
    for (int nt = 0; nt < 4; ++nt) {
      int col = wcol + nt * 16 + l15;
      bh[nt] = *(const f16x8*)&Lds[cur][2][col * 32 + ((quad ^ swz) * 8)];
      bl[nt] = *(const f16x8*)&Lds[cur][3][col * 32 + ((quad ^ swz) * 8)];
    }
    __builtin_amdgcn_s_setprio(1);
#pragma unroll
    for (int mt = 0; mt < 4; ++mt)
#pragma unroll
      for (int nt = 0; nt < 4; ++nt) {
        acc[mt][nt] = __builtin_amdgcn_mfma_f32_16x16x32_f16(ah[mt], bh[nt], acc[mt][nt], 0, 0, 0);
        acc[mt][nt] = __builtin_amdgcn_mfma_f32_16x16x32_f16(ah[mt], bl[nt], acc[mt][nt], 0, 0, 0);
        acc[mt][nt] = __builtin_amdgcn_mfma_f32_16x16x32_f16(al[mt], bh[nt], acc[mt][nt], 0, 0, 0);
      }
    __builtin_amdgcn_s_setprio(0);
    __syncthreads();   // drains this iter's prefetch + releases cur for overwrite
  }
  bool diag = (bi == bj);
#pragma unroll
  for (int mt = 0; mt < 4; ++mt)
#pragma unroll
    for (int nt = 0; nt < 4; ++nt)
#pragma unroll
      for (int rg = 0; rg < 4; ++rg) {
        int row = i0 + wr + mt * 16 + quad * 4 + rg;
        int col = j0 + wcol + nt * 16 + l15;
        float v = acc[mt][nt][rg];
        eout[(size_t)row * CCH + col] = v;
        if (!diag) eout[(size_t)col * CCH + row] = v;
      }
}

// ------- softmax: attn[i][j] = gamma * exp(rowmin - E)/sum + (i==j), f16 out,
// ------- E = E0 (+ E1 if two) -------------------------------------------------
__global__ void softmax_kernel(const float* __restrict__ e0, const float* __restrict__ e1,
                               int two, const float* __restrict__ gamma_p,
                               f16* __restrict__ attn) {
  int i = blockIdx.x, ib = blockIdx.y;
  const float* r0 = e0 + ((size_t)ib * CCH + i) * CCH;
  const float* r1 = e1 + ((size_t)ib * CCH + i) * CCH;
  f16* arow = attn + ((size_t)ib * CCH + i) * CCH;
  int t = threadIdx.x;
  f32x4 v0 = *(const f32x4*)(r0 + t * 8);
  f32x4 v1 = *(const f32x4*)(r0 + t * 8 + 4);
  if (two) {
    f32x4 u0 = *(const f32x4*)(r1 + t * 8);
    f32x4 u1 = *(const f32x4*)(r1 + t * 8 + 4);
#pragma unroll
    for (int u = 0; u < 4; ++u) { v0[u] += u0[u]; v1[u] += u1[u]; }
  }
  float m = v0[0];
#pragma unroll
  for (int u = 1; u < 4; ++u) m = fminf(m, v0[u]);
#pragma unroll
  for (int u = 0; u < 4; ++u) m = fminf(m, v1[u]);
#pragma unroll
  for (int off = 32; off > 0; off >>= 1) m = fminf(m, __shfl_xor(m, off));
  __shared__ float redA[4], redB[4];
  if ((t & 63) == 0) redA[t >> 6] = m;
  __syncthreads();
  m = fminf(fminf(redA[0], redA[1]), fminf(redA[2], redA[3]));
  float e[8], s = 0.f;
#pragma unroll
  for (int u = 0; u < 4; ++u) { e[u] = __expf(m - v0[u]); s += e[u]; }
#pragma unroll
  for (int u = 0; u < 4; ++u) { e[4 + u] = __expf(m - v1[u]); s += e[4 + u]; }
#pragma unroll
  for (int off = 32; off > 0; off >>= 1) s += __shfl_xor(s, off);
  if ((t & 63) == 0) redB[t >> 6] = s;
  __syncthreads();
  s = redB[0] + redB[1] + redB[2] + redB[3];
  float gamma = *gamma_p;
  float ginv = gamma / s;
  int du = i - t * 8;   // in [0,8) only for the thread owning the diagonal element
  f16x8 o;
#pragma unroll
  for (int u = 0; u < 8; ++u) {
    float v = e[u] * ginv;
    if (u == du) v += 1.0f;
    o[u] = (f16)v;
  }
  *(f16x8*)(arow + t * 8) = o;
}

// ---------------- GEMM2: out = c2s(attn' @ q), attn' = gamma*attn + I ----
// 256x256 tile (128 FLOP/byte feed intensity), 512 threads / 8 waves,
// double-buffered 2-barrier pipeline, XCD-swizzled, 4-phase staged epilogue.
__global__ __launch_bounds__(512) void gemm2_kernel(const f16* __restrict__ attn,
                                                    const f16* __restrict__ qhT,
                                                    float* __restrict__ out, int b0) {
  int ib = blockIdx.z;
  // XCD-aware bijective swizzle over the 8x16 = 128 (x,y) block space.
  int lin = blockIdx.x + gridDim.x * blockIdx.y;           // 0..127
  int nwg = gridDim.x * gridDim.y;
  int cpx = nwg >> 3;                                      // 16
  int lin2 = (lin & 7) * cpx + (lin >> 3);
  int i0 = (lin2 & 7) * 256;       // channel (cd) tile
  int n0 = (lin2 >> 3) * 256;      // spatial (n) tile
  // 2 bufs x {A,B} x 256x32 f16 = 64 KB; reused as 16384 f32 for the epilogue.
  __shared__ f16 Lds[2][2][256 * 32];
  int tid = threadIdx.x;
  int lane = tid & 63, wv = tid >> 6;        // wv 0..7
  int l15 = lane & 15, quad = lane >> 4;
  int wr = (wv >> 2) * 128;                  // ch offset: 0 or 128
  int wcol = (wv & 3) * 64;                  // n offset: 0,64,128,192
  int swz = (l15 >> 1) & 3;
  int kbs = (lane & 3) ^ ((lane >> 3) & 3);

  int arr = wv >> 2, rsub = wv & 3;   // staging role: arr 0 -> A (attn), 1 -> B (qhT)
  const f16* gbase = arr ? (qhT + ((size_t)ib * NSP + n0) * CCH)
                         : (attn + ((size_t)ib * CCH + i0) * CCH);
  const f16* gsrc = gbase + (size_t)(rsub * 64 + (lane >> 2)) * CCH + kbs * 8;

  auto stage = [&](int buf, int kk) {
#pragma unroll
    for (int t = 0; t < 4; ++t)
      gld16(gsrc + (size_t)(t * 16) * CCH + kk,
            &Lds[buf][arr][(rsub * 64 + t * 16) * 32]);
  };

  const f32x4 vzero = {0.f, 0.f, 0.f, 0.f};
  f32x4 acc[8][4];
#pragma unroll
  for (int a = 0; a < 8; ++a)
#pragma unroll
    for (int bq = 0; bq < 4; ++bq) acc[a][bq] = vzero;

  const int nk = CCH >> 5;   // 64
  stage(0, 0);
  __syncthreads();
  for (int it = 0; it < nk; ++it) {
    int cur = it & 1;
    if (it + 1 < nk) stage(cur ^ 1, (it + 1) << 5);
    f16x8 af[8], bf[4];
#pragma unroll
    for (int mt = 0; mt < 8; ++mt)
      af[mt] = *(const f16x8*)&Lds[cur][0][(wr + mt * 16 + l15) * 32 + ((quad ^ swz) * 8)];
#pragma unroll
    for (int nt = 0; nt < 4; ++nt)
      bf[nt] = *(const f16x8*)&Lds[cur][1][(wcol + nt * 16 + l15) * 32 + ((quad ^ swz) * 8)];
    __builtin_amdgcn_s_setprio(1);
#pragma unroll
    for (int mt = 0; mt < 8; ++mt)
#pragma unroll
      for (int nt = 0; nt < 4; ++nt)
        acc[mt][nt] = __builtin_amdgcn_mfma_f32_16x16x32_f16(af[mt], bf[nt], acc[mt][nt], 0, 0, 0);
    __builtin_amdgcn_s_setprio(0);
    __syncthreads();
  }

  // ---- epilogue: 4 phases of (ch-half h, n-half nh); each phase stages a
  // ---- 128ch x 128n unit as [g][jh][id][f] f32 in LDS, then coalesced store.
  float* eld = (float*)&Lds[0][0][0];   // 16384 f32 = 64 KB
  int b = b0 + ib;
#pragma unroll
  for (int p = 0; p < 4; ++p) {
    __syncthreads();
    if ((wv >> 1) == p) {               // 2 waves own this 128x128 unit
#pragma unroll
      for (int mt = 0; mt < 8; ++mt) {
        int f = mt >> 1;                 // (ch>>5)&3
        int gb2 = (mt & 1) * 16 + quad * 4;  // ch&31 base
#pragma unroll
        for (int nt = 0; nt < 4; ++nt) {
          int jh = (wv & 1) * 4 + nt;    // ihh-local 0..7
#pragma unroll
          for (int rg = 0; rg < 4; ++rg)
            eld[(gb2 + rg) * 512 + jh * 64 + l15 * 4 + f] = acc[mt][nt][rg];
        }
      }
    }
    __syncthreads();
    int h = p >> 1, nh = p & 1;
    int e = (i0 >> 7) + h;
    int W = (n0 >> 8) * 4 + (e >> 2);
    int H0 = (e & 3) * 16 + nh * 8;
#pragma unroll
    for (int u = 0; u < 4; ++u) {
      int g = wv * 4 + u;
      size_t goff = ((((size_t)b * 32 + g) * 64 + W) * 4096) + (size_t)H0 * 64;
#pragma unroll
      for (int hv = 0; hv < 2; ++hv) {
        int fo = hv * 256 + lane * 4;
        *(f32x4*)(out + goff + fo) = *(const f32x4*)&eld[g * 512 + fo];
      }
    }
  }
}

extern "C" void kernel_launch(void* const* d_in, const int* in_sizes, int n_in,
                              void* d_out, int out_size, void* d_ws, size_t ws_size,
                              hipStream_t stream) {
  const float* x = (const float*)d_in[0];
  const float* gamma = (const float*)d_in[1];
  float* out = (float*)d_out;

  const size_t szQ = (size_t)CCH * NSP;  // 8M elements
  const size_t szE = (size_t)CCH * CCH;  // 4M elements

  // bytes per batch: 3 f16 q-arrays + ksplit fp32 energy arrays + f16 attn
  const size_t pbSplit = szQ * 2 * 3 + szE * 4 * 2 + szE * 2;  // 90 MB
  const size_t pbNoSplit = szQ * 2 * 3 + szE * 4 + szE * 2;    // 73 MB

  int ksplit, nb;
  if (ws_size >= (size_t)NB * pbSplit) { ksplit = 2; nb = NB; }
  else if (ws_size >= (size_t)NB * pbNoSplit) { ksplit = 1; nb = NB; }
  else { ksplit = 1; nb = 1; }

  char* p = (char*)d_ws;
  f16* qh = (f16*)p;   p += (size_t)nb * szQ * 2;
  f16* ql = (f16*)p;   p += (size_t)nb * szQ * 2;
  f16* qhT = (f16*)p;  p += (size_t)nb * szQ * 2;
  float* energy = (float*)p; p += (size_t)nb * szE * 4 * ksplit;
  f16* attn = (f16*)p;
  const float* e1 = (ksplit == 2) ? (energy + (size_t)nb * szE) : energy;

  for (int b0 = 0; b0 < NB; b0 += nb) {
    pack_kernel<<<nb * 8192, 256, 0, stream>>>(x, qh, ql, b0);
    transpose_kernel<<<dim3(32, 64, nb), 256, 0, stream>>>(qh, qhT);
    gemm1_kernel<<<dim3(136 * ksplit, 1, nb), 256, 0, stream>>>(qh, ql, energy, ksplit);
    softmax_kernel<<<dim3(CCH, nb), 256, 0, stream>>>(energy, e1, ksplit - 1, gamma, attn);
    gemm2_kernel<<<dim3(8, 16, nb), 512, 0, stream>>>(attn, qhT, out, b0);
  }
}

// Round 11
// 682.298 us; speedup vs baseline: 1.1222x; 1.0102x over previous
//
#include <hip/hip_runtime.h>

typedef _Float16 f16;
typedef __attribute__((ext_vector_type(8))) _Float16 f16x8;
typedef __attribute__((ext_vector_type(4))) float f32x4;

#define CCH 2048   // channels after space_to_channel (32*4^3)
#define NSP 4096   // spatial after s2c (16^3)
#define NB  4      // batch

#define CFENCE asm volatile("" ::: "memory")

__device__ __forceinline__ void gld16(const void* g, void* l) {
  __builtin_amdgcn_global_load_lds(
      (const __attribute__((address_space(1))) void*)g,
      (__attribute__((address_space(3))) void*)l, 16, 0, 0);
}

// ---------------- pack: x (B,32,64,64,64) fp32 -> qh/ql f16 [ib][cc][n] ----------------
__global__ void pack_kernel(const float* __restrict__ x, f16* __restrict__ qh,
                            f16* __restrict__ ql, int b0) {
  int gid = blockIdx.x * 256 + threadIdx.x;
  int n = gid & (NSP - 1);
  int t = gid >> 12;
  int c = t & 31; t >>= 5;
  int r = t & 15; int ib = t >> 4;
  int wc = n >> 8, hc = (n >> 4) & 15, dc = n & 15;
  int w = wc * 4 + (hc >> 2);
  int h = (hc & 3) * 16 + r;
  int b = b0 + ib;
  const f32x4 v = *(const f32x4*)(x + ((((size_t)b * 32 + c) * 64 + w) * 64 + h) * 64 + dc * 4);
#pragma unroll
  for (int bd = 0; bd < 4; ++bd) {
    int cc = r * 128 + bd * 32 + c;
    size_t o = ((size_t)ib * CCH + cc) * NSP + n;
    float val = v[bd];
    f16 hi = (f16)val;
    qh[o] = hi;
    ql[o] = (f16)(val - (float)hi);
  }
}

// ---------------- transpose: qh [ib][j][n] -> qhT [ib][n][j] ----------------
__global__ void transpose_kernel(const f16* __restrict__ qh, f16* __restrict__ qhT) {
  int ib = blockIdx.z;
  int j0 = blockIdx.x * 64, n0 = blockIdx.y * 64;
  __shared__ f16 tile[64][72];
  int t = threadIdx.x;
  int r = t >> 3;            // 0..31
  int cb = (t & 7) * 8;      // 0..56
#pragma unroll
  for (int half = 0; half < 2; ++half) {
    int rr = r + half * 32;
    f16x8 v = *(const f16x8*)(qh + ((size_t)ib * CCH + j0 + rr) * NSP + n0 + cb);
    *(f16x8*)&tile[rr][cb] = v;
  }
  __syncthreads();
#pragma unroll
  for (int half = 0; half < 2; ++half) {
    int rr = r + half * 32;
    f16x8 o;
#pragma unroll
    for (int u = 0; u < 8; ++u) o[u] = tile[cb + u][rr];
    *(f16x8*)(qhT + ((size_t)ib * NSP + n0 + rr) * CCH + j0 + cb) = o;
  }
}

// -------- GEMM1: energy = q q^T, split f16 (hh+hl+lh), upper-triangle blocks,
// -------- double-buffered 2-phase pipeline, ksplit=2 K-partition (proven 265us).
__global__ __launch_bounds__(256) void gemm1_kernel(const f16* __restrict__ qh,
                                                    const f16* __restrict__ ql,
                                                    float* __restrict__ energy,
                                                    int ksplit) {
  int ib = blockIdx.z;
  int nwg = gridDim.x;
  int cpx = nwg >> 3;
  int bx = blockIdx.x;
  int tri = (bx & 7) * cpx + (bx >> 3);
  int ks = 0;
  if (ksplit == 2) { ks = tri >= 136; tri -= ks * 136; }
  int rem = tri, bi = 0, span = 16;
  while (rem >= span) { rem -= span; ++bi; --span; }
  int bj = bi + rem;
  int i0 = bi * 128, j0 = bj * 128;
  int kbeg = ks * 2048;
  int kend = (ksplit == 2) ? kbeg + 2048 : NSP;
  float* eout = energy + ((size_t)(ks * gridDim.z + ib)) * CCH * CCH;

  __shared__ f16 Lds[2][4][128 * 32];   // [buf][Ah,Al,Bh,Bl] = 64 KB
  int tid = threadIdx.x;
  int lane = tid & 63, wv = tid >> 6;
  int l15 = lane & 15, quad = lane >> 4;
  int wr = (wv >> 1) * 64, wcol = (wv & 1) * 64;
  int swz = (l15 >> 1) & 3;
  int kbs = (lane & 3) ^ ((lane >> 3) & 3);

  const f16* srcA = (wv & 1) ? ql : qh;
  int rbase = (wv < 2) ? i0 : j0;
  const f16* gsrc = srcA + ((size_t)ib * CCH + rbase) * NSP
                    + (size_t)(lane >> 2) * NSP + kbs * 8;

  auto stage = [&](int buf, int kk) {
    f16* ld = &Lds[buf][wv][0];
#pragma unroll
    for (int t = 0; t < 8; ++t)
      gld16(gsrc + (size_t)(t * 16) * NSP + kk, ld + t * 512);
  };

  const f32x4 vzero = {0.f, 0.f, 0.f, 0.f};
  f32x4 acc[4][4];
#pragma unroll
  for (int a = 0; a < 4; ++a)
#pragma unroll
    for (int bq = 0; bq < 4; ++bq) acc[a][bq] = vzero;

  int nk = (kend - kbeg) >> 5;
  stage(0, kbeg);
  __syncthreads();
  for (int it = 0; it < nk; ++it) {
    int cur = it & 1;
    if (it + 1 < nk) stage(cur ^ 1, kbeg + ((it + 1) << 5));
    f16x8 ah[4], al[4], bh[4], bl[4];
#pragma unroll
    for (int mt = 0; mt < 4; ++mt) {
      int row = wr + mt * 16 + l15;
      ah[mt] = *(const f16x8*)&Lds[cur][0][row * 32 + ((quad ^ swz) * 8)];
      al[mt] = *(const f16x8*)&Lds[cur][1][row * 32 + ((quad ^ swz) * 8)];
    }
#pragma unroll
    for (int nt = 0; nt < 4; ++nt) {
      int col = wcol + nt * 16 + l15;
      bh[nt] = *(const f16x8*)&Lds[cur][2][col * 32 + ((quad ^ swz) * 8)];
      bl[nt] = *(const f16x8*)&Lds[cur][3][col * 32 + ((quad ^ swz) * 8)];
    }
    __builtin_amdgcn_s_setprio(1);
#pragma unroll
    for (int mt = 0; mt < 4; ++mt)
#pragma unroll
      for (int nt = 0; nt < 4; ++nt) {
        acc[mt][nt] = __builtin_amdgcn_mfma_f32_16x16x32_f16(ah[mt], bh[nt], acc[mt][nt], 0, 0, 0);
        acc[mt][nt] = __builtin_amdgcn_mfma_f32_16x16x32_f16(ah[mt], bl[nt], acc[mt][nt], 0, 0, 0);
        acc[mt][nt] = __builtin_amdgcn_mfma_f32_16x16x32_f16(al[mt], bh[nt], acc[mt][nt], 0, 0, 0);
      }
    __builtin_amdgcn_s_setprio(0);
    __syncthreads();
  }
  bool diag = (bi == bj);
#pragma unroll
  for (int mt = 0; mt < 4; ++mt)
#pragma unroll
    for (int nt = 0; nt < 4; ++nt)
#pragma unroll
      for (int rg = 0; rg < 4; ++rg) {
        int row = i0 + wr + mt * 16 + quad * 4 + rg;
        int col = j0 + wcol + nt * 16 + l15;
        float v = acc[mt][nt][rg];
        eout[(size_t)row * CCH + col] = v;
        if (!diag) eout[(size_t)col * CCH + row] = v;
      }
}

// ------- softmax: attn[i][j] = gamma * exp(rowmin - E)/sum + (i==j), f16 out,
// ------- E = E0 (+ E1 if two) -------------------------------------------------
__global__ void softmax_kernel(const float* __restrict__ e0, const float* __restrict__ e1,
                               int two, const float* __restrict__ gamma_p,
                               f16* __restrict__ attn) {
  int i = blockIdx.x, ib = blockIdx.y;
  const float* r0 = e0 + ((size_t)ib * CCH + i) * CCH;
  const float* r1 = e1 + ((size_t)ib * CCH + i) * CCH;
  f16* arow = attn + ((size_t)ib * CCH + i) * CCH;
  int t = threadIdx.x;
  f32x4 v0 = *(const f32x4*)(r0 + t * 8);
  f32x4 v1 = *(const f32x4*)(r0 + t * 8 + 4);
  if (two) {
    f32x4 u0 = *(const f32x4*)(r1 + t * 8);
    f32x4 u1 = *(const f32x4*)(r1 + t * 8 + 4);
#pragma unroll
    for (int u = 0; u < 4; ++u) { v0[u] += u0[u]; v1[u] += u1[u]; }
  }
  float m = v0[0];
#pragma unroll
  for (int u = 1; u < 4; ++u) m = fminf(m, v0[u]);
#pragma unroll
  for (int u = 0; u < 4; ++u) m = fminf(m, v1[u]);
#pragma unroll
  for (int off = 32; off > 0; off >>= 1) m = fminf(m, __shfl_xor(m, off));
  __shared__ float redA[4], redB[4];
  if ((t & 63) == 0) redA[t >> 6] = m;
  __syncthreads();
  m = fminf(fminf(redA[0], redA[1]), fminf(redA[2], redA[3]));
  float e[8], s = 0.f;
#pragma unroll
  for (int u = 0; u < 4; ++u) { e[u] = __expf(m - v0[u]); s += e[u]; }
#pragma unroll
  for (int u = 0; u < 4; ++u) { e[4 + u] = __expf(m - v1[u]); s += e[4 + u]; }
#pragma unroll
  for (int off = 32; off > 0; off >>= 1) s += __shfl_xor(s, off);
  if ((t & 63) == 0) redB[t >> 6] = s;
  __syncthreads();
  s = redB[0] + redB[1] + redB[2] + redB[3];
  float gamma = *gamma_p;
  float ginv = gamma / s;
  int du = i - t * 8;
  f16x8 o;
#pragma unroll
  for (int u = 0; u < 8; ++u) {
    float v = e[u] * ginv;
    if (u == du) v += 1.0f;
    o[u] = (f16)v;
  }
  *(f16x8*)(arow + t * 8) = o;
}

// ---------------- GEMM2: out = c2s(attn' @ q), attn' = gamma*attn + I ----
// 8-phase 256x256 template: BK=64, 128 KB dynamic LDS [dbuf][A,B][half][128][64],
// per-phase {swizzled ds_read || half-tile gld16 -> barrier -> 16 MFMA -> barrier},
// vmcnt(0) only at phases 4/8 (once per K-tile), XOR row-swizzle (conflict-free),
// pre-swizzled global source + linear gld16 dest (rule #21).
// One phase = (MTH: mfrag-half, KS: k-step) quadrant of the wave's 128x64 C-tile.
#define G2_PHASE(D, DN, MTH, KS, SKT, SMAT, SHALF, CK) do {                         \
    const int k8p = ((KS)*4 + quad) ^ (l15 & 7);                                    \
    f16x8 af[4], bf[4];                                                             \
    _Pragma("unroll")                                                               \
    for (int m2 = 0; m2 < 4; ++m2)                                                  \
      af[m2] = *(const f16x8*)&lds[(((D)*2 + 0)*2 + hA)*8192 +                      \
                                   ((MTH)*64 + m2*16 + l15)*64 + k8p*8];            \
    _Pragma("unroll")                                                               \
    for (int n2 = 0; n2 < 4; ++n2)                                                  \
      bf[n2] = *(const f16x8*)&lds[(((D)*2 + 1)*2 + hB)*8192 +                      \
                                   (bofs + n2*16 + l15)*64 + k8p*8];                \
    if ((SKT) < 32) {                                                               \
      const f16* s_ = ((SMAT) ? bsrc : asrc)                                        \
                      + (size_t)((SHALF)*128 + srow0)*CCH + (SKT)*64 + k8s*8;       \
      f16* d_ = lds + (((DN)*2 + (SMAT))*2 + (SHALF))*8192 + srow0*64 + k8d*8;      \
      gld16(s_, d_);                                                                \
      gld16(s_ + (size_t)64*CCH, d_ + 4096);                                        \
    }                                                                               \
    CFENCE; __builtin_amdgcn_s_barrier(); CFENCE;                                   \
    __builtin_amdgcn_s_setprio(1);                                                  \
    _Pragma("unroll")                                                               \
    for (int m2 = 0; m2 < 4; ++m2)                                                  \
      _Pragma("unroll")                                                             \
      for (int n2 = 0; n2 < 4; ++n2)                                                \
        acc[(MTH)*4 + m2][n2] = __builtin_amdgcn_mfma_f32_16x16x32_f16(             \
            af[m2], bf[n2], acc[(MTH)*4 + m2][n2], 0, 0, 0);                        \
    __builtin_amdgcn_s_setprio(0);                                                  \
    if (CK) { asm volatile("s_waitcnt vmcnt(0)" ::: "memory"); }                    \
    CFENCE; __builtin_amdgcn_s_barrier(); CFENCE;                                   \
  } while (0)

__global__ __launch_bounds__(512) void gemm2_kernel(const f16* __restrict__ attn,
                                                    const f16* __restrict__ qhT,
                                                    float* __restrict__ out, int b0) {
  extern __shared__ f16 lds[];   // 128 KB
  int ib = blockIdx.z;
  // XCD-aware bijective swizzle over the 8x16 = 128 (x,y) block space.
  int lin = blockIdx.x + gridDim.x * blockIdx.y;           // 0..127
  int nwg = gridDim.x * gridDim.y;
  int cpx = nwg >> 3;                                      // 16
  int lin2 = (lin & 7) * cpx + (lin >> 3);
  int i0 = (lin2 & 7) * 256;       // channel (cd) tile
  int n0 = (lin2 >> 3) * 256;      // spatial (n) tile

  int tid = threadIdx.x;
  int lane = tid & 63, wv = tid >> 6;        // wv 0..7
  int l15 = lane & 15, quad = lane >> 4;
  const int hA = wv >> 2;                    // wave's A-half (ch 0-127 / 128-255)
  const int hB = (wv & 3) >> 1;              // wave's B-half (n 0-127 / 128-255)
  const int bofs = (wv & 1) * 64;            // wave's n-offset within B-half
  // staging lane mapping: 2 gld16/thread per half-tile, wave dest = base+lane*16
  const int srow0 = tid >> 3;                              // 0..63 (+64 second pass)
  const int k8s = (tid & 7) ^ (srow0 & 7);                 // pre-swizzled source k8
  const int k8d = tid & 7;                                 // linear dest k8

  const f16* asrc = attn + ((size_t)ib * CCH + i0) * CCH;
  const f16* bsrc = qhT + ((size_t)ib * NSP + n0) * CCH;

  const f32x4 vzero = {0.f, 0.f, 0.f, 0.f};
  f32x4 acc[8][4];
#pragma unroll
  for (int a = 0; a < 8; ++a)
#pragma unroll
    for (int bq = 0; bq < 4; ++bq) acc[a][bq] = vzero;

  // prologue: stage tile 0 (4 half-tiles) into dbuf0, drain, rendezvous
  {
#pragma unroll
    for (int sm = 0; sm < 2; ++sm)
#pragma unroll
      for (int sh = 0; sh < 2; ++sh) {
        const f16* s_ = (sm ? bsrc : asrc) + (size_t)(sh * 128 + srow0) * CCH + k8s * 8;
        f16* d_ = lds + ((0 * 2 + sm) * 2 + sh) * 8192 + srow0 * 64 + k8d * 8;
        gld16(s_, d_);
        gld16(s_ + (size_t)64 * CCH, d_ + 4096);
      }
    asm volatile("s_waitcnt vmcnt(0)" ::: "memory");
    CFENCE; __builtin_amdgcn_s_barrier(); CFENCE;
  }

  // main loop: iteration it handles K-tiles 2it (dbuf0) and 2it+1 (dbuf1);
  // ph1-4 stage odd tile 2it+1 -> dbuf1 (consumed ph5-8, fenced at ph4);
  // ph5-8 stage even tile 2it+2 -> dbuf0 (consumed next iter, fenced at ph8).
  for (int it = 0; it < 16; ++it) {
    int t1 = 2 * it + 1, t2 = 2 * it + 2;
    G2_PHASE(0, 1, 0, 0, t1, 0, 0, 0);
    G2_PHASE(0, 1, 1, 0, t1, 1, 0, 0);
    G2_PHASE(0, 1, 0, 1, t1, 0, 1, 0);
    G2_PHASE(0, 1, 1, 1, t1, 1, 1, 1);
    G2_PHASE(1, 0, 0, 0, t2, 0, 0, 0);
    G2_PHASE(1, 0, 1, 0, t2, 1, 0, 0);
    G2_PHASE(1, 0, 0, 1, t2, 0, 1, 0);
    G2_PHASE(1, 0, 1, 1, t2, 1, 1, 1);
  }

  __syncthreads();
  // ---- epilogue: 4 phases of (ch-half h, n-half nh); each stages a 128x128 unit
  // ---- as [g][jh][id][f] f32 in LDS, then fully-coalesced f32x4 store.
  float* eld = (float*)lds;   // 16384 f32 = 64 KB
  int b = b0 + ib;
#pragma unroll
  for (int p = 0; p < 4; ++p) {
    __syncthreads();
    if ((wv >> 1) == p) {               // 2 waves own this 128x128 unit
#pragma unroll
      for (int mt = 0; mt < 8; ++mt) {
        int f = mt >> 1;                 // (ch>>5)&3
        int gb2 = (mt & 1) * 16 + quad * 4;  // ch&31 base
#pragma unroll
        for (int nt = 0; nt < 4; ++nt) {
          int jh = (wv & 1) * 4 + nt;    // ihh-local 0..7
#pragma unroll
          for (int rg = 0; rg < 4; ++rg)
            eld[(gb2 + rg) * 512 + jh * 64 + l15 * 4 + f] = acc[mt][nt][rg];
        }
      }
    }
    __syncthreads();
    int h = p >> 1, nh = p & 1;
    int e = (i0 >> 7) + h;
    int W = (n0 >> 8) * 4 + (e >> 2);
    int H0 = (e & 3) * 16 + nh * 8;
#pragma unroll
    for (int u = 0; u < 4; ++u) {
      int g = wv * 4 + u;
      size_t goff = ((((size_t)b * 32 + g) * 64 + W) * 4096) + (size_t)H0 * 64;
#pragma unroll
      for (int hv = 0; hv < 2; ++hv) {
        int fo = hv * 256 + lane * 4;
        *(f32x4*)(out + goff + fo) = *(const f32x4*)&eld[g * 512 + fo];
      }
    }
  }
}

extern "C" void kernel_launch(void* const* d_in, const int* in_sizes, int n_in,
                              void* d_out, int out_size, void* d_ws, size_t ws_size,
                              hipStream_t stream) {
  const float* x = (const float*)d_in[0];
  const float* gamma = (const float*)d_in[1];
  float* out = (float*)d_out;

  static bool g2cfg = false;
  if (!g2cfg) {
    hipFuncSetAttribute(reinterpret_cast<const void*>(gemm2_kernel),
                        hipFuncAttributeMaxDynamicSharedMemorySize, 131072);
    g2cfg = true;
  }

  const size_t szQ = (size_t)CCH * NSP;  // 8M elements
  const size_t szE = (size_t)CCH * CCH;  // 4M elements

  const size_t pbSplit = szQ * 2 * 3 + szE * 4 * 2 + szE * 2;  // 90 MB
  const size_t pbNoSplit = szQ * 2 * 3 + szE * 4 + szE * 2;    // 73 MB

  int ksplit, nb;
  if (ws_size >= (size_t)NB * pbSplit) { ksplit = 2; nb = NB; }
  else if (ws_size >= (size_t)NB * pbNoSplit) { ksplit = 1; nb = NB; }
  else { ksplit = 1; nb = 1; }

  char* p = (char*)d_ws;
  f16* qh = (f16*)p;   p += (size_t)nb * szQ * 2;
  f16* ql = (f16*)p;   p += (size_t)nb * szQ * 2;
  f16* qhT = (f16*)p;  p += (size_t)nb * szQ * 2;
  float* energy = (float*)p; p += (size_t)nb * szE * 4 * ksplit;
  f16* attn = (f16*)p;
  const float* e1 = (ksplit == 2) ? (energy + (size_t)nb * szE) : energy;

  for (int b0 = 0; b0 < NB; b0 += nb) {
    pack_kernel<<<nb * 8192, 256, 0, stream>>>(x, qh, ql, b0);
    transpose_kernel<<<dim3(32, 64, nb), 256, 0, stream>>>(qh, qhT);
    gemm1_kernel<<<dim3(136 * ksplit, 1, nb), 256, 0, stream>>>(qh, ql, energy, ksplit);
    softmax_kernel<<<dim3(CCH, nb), 256, 0, stream>>>(energy, e1, ksplit - 1, gamma, attn);
    gemm2_kernel<<<dim3(8, 16, nb), 512, 131072, stream>>>(attn, qhT, out, b0);
  }
}